// Round 11
// baseline (421.348 us; speedup 1.0000x reference)
//
#include <hip/hip_runtime.h>
#include <stdint.h>

// Problem constants: x [B=2, S=4096, K=4096] -> M = 8192; weight [N=4096, K=4096]
#define M_DIM 8192
#define N_DIM 4096
#define K_DIM 4096

using int4v = __attribute__((ext_vector_type(4))) int;

// ---------------------------------------------------------------------------
// Pack kernel: int32 (widened int8 in [-127,127]) -> int8 bytes.
// ---------------------------------------------------------------------------
__global__ __launch_bounds__(256) void pack_kernel(const int4* __restrict__ sx,
                                                   const int4* __restrict__ sw,
                                                   unsigned int* __restrict__ dst,
                                                   int nx, int ntot) {
    int idx = blockIdx.x * blockDim.x + threadIdx.x;
    if (idx >= ntot) return;
    int4 v = (idx < nx) ? sx[idx] : sw[idx - nx];
    dst[idx] = (v.x & 0xff) | ((v.y & 0xff) << 8) | ((v.z & 0xff) << 16) |
               ((v.w & 0xff) << 24);
}

// ---------------------------------------------------------------------------
// i8 GEMM, PRODUCER-CONSUMER WAVE SPECIALIZATION (r11).
//
// r2-r10: every barrier-synchronized structure lands at 172-181 us (40% of
// i8 MFMA ceiling) -- the documented m97-family plateau. Cause: every wave
// both stages and computes, so staging latency + the __syncthreads
// vmcnt(0)+lgkmcnt(0) drain sit on every wave's critical path.
//
// This kernel has ZERO barriers in the K-loop. 512 threads = 8 waves:
//   waves 0-3: compute (r7's exact 64x64 tile, 4x4 of mfma_i32_16x16x64_i8)
//   waves 4-6: producers feeding a 3-slot LDS ring (slot = 16 KiB A+B tile)
//   wave  7 : idle
// Sync via LDS flags: ready[s] = staged-tile generation (single producer
// writer per slot), done[s] = consumer count (4 per tile, atomicAdd lane 0).
// __threadfence_block() orders data ds_writes/reads vs flag accesses.
// All 8 waves of a block are co-resident -> spins cannot deadlock.
// Producers prefetch the next tile's 16 b128 global loads into registers
// right after staging the current one -> global latency overlaps the
// done-wait + consumer compute; compute waves run pure ds_read->MFMA.
//
// LDS: 3 x (8 KiB A + 8 KiB B) + flags ~= 48 KiB -> 2 blocks/CU (regs
// capped 128 via __launch_bounds__(512,4): 16 waves/CU).
// Bank swizzle (r5, measured 0 conflicts): LDS 16-B chunk (row, gs) holds
// global col-group gs ^ ((row>>1)&3); consumers XOR-correct (key (fr>>1)&3).
//
// C[m,n] = sum_k x[m,k] * w[n,k]  (both operands K-major).
// A/B frag: m=lane&15, k-group=lane>>4.  C/D: col=lane&15, row=(lane>>4)*4+reg.
// ---------------------------------------------------------------------------
__global__ __launch_bounds__(512, 4) void gemm_i8_kernel(
    const char* __restrict__ Aq,   // [M, K] int8
    const char* __restrict__ Bq,   // [N, K] int8
    const int* __restrict__ bias,  // [N] int32 (widened int8)
    const float* __restrict__ a_ptr,
    const float* __restrict__ b_ptr,
    int32_t* __restrict__ out)     // [M, N] int32 holding int8 values
{
    __shared__ char As[3][128 * 64];   // 3 x 8 KiB
    __shared__ char Bs[3][128 * 64];   // 3 x 8 KiB
    __shared__ int  ready[3];
    __shared__ int  done[3];

    const int tid  = threadIdx.x;
    const int lane = tid & 63;
    const int wave = tid >> 6;
    const int m0   = blockIdx.y * 128;
    const int n0   = blockIdx.x * 128;

    if (tid < 3) { ready[tid] = 0; done[tid] = 0; }
    __syncthreads();  // flags visible to all waves (only barrier in kernel)

    if (wave >= 4) {
        // ------------------------- PRODUCER -------------------------------
        const int p = wave - 4;
        if (p >= 3) return;  // wave 7 idle
        // Lane covers 16-B chunk: rows crow+16i, swizzled col-group.
        const int crow = lane >> 2;             // 0..15
        const int ccol = lane & 3;
        const int lbase = crow * 64 + ccol * 16;
        // swizzle key for row = 16i+crow is (crow>>1)&3 (16i = 0 mod 8)
        const int gcol = (ccol ^ ((crow >> 1) & 3)) * 16;
        const char* aBase = Aq + (size_t)(m0 + crow) * K_DIM + gcol;
        const char* bBase = Bq + (size_t)(n0 + crow) * K_DIM + gcol;
        const size_t r16 = (size_t)16 * K_DIM;

        int4v ar[8], br[8];
        // Prologue: load tile t = p into registers.
#pragma unroll
        for (int i = 0; i < 8; ++i) {
            ar[i] = *(const int4v*)(aBase + (size_t)i * r16 + p * 64);
            br[i] = *(const int4v*)(bBase + (size_t)i * r16 + p * 64);
        }

        int m = 0;
        for (int t = p; t < 64; t += 3, ++m) {
            // Wait until all 4 consumers finished tile t-3 in this slot.
            while (*(volatile int*)&done[p] < 4 * m)
                __builtin_amdgcn_s_sleep(1);
            // Stage tile t from registers (vmcnt waits are ~1 tile old).
#pragma unroll
            for (int i = 0; i < 8; ++i) {
                *(int4v*)&As[p][lbase + i * 1024] = ar[i];
                *(int4v*)&Bs[p][lbase + i * 1024] = br[i];
            }
            __threadfence_block();          // ds_writes retired before flag
            if (lane == 0) *(volatile int*)&ready[p] = t + 1;
            // Prefetch this producer's next tile (t+3).
            if (t + 3 < 64) {
#pragma unroll
                for (int i = 0; i < 8; ++i) {
                    ar[i] = *(const int4v*)(aBase + (size_t)i * r16 + (t + 3) * 64);
                    br[i] = *(const int4v*)(bBase + (size_t)i * r16 + (t + 3) * 64);
                }
            }
        }
        return;
    }

    // --------------------------- CONSUMER ---------------------------------
    const int wr = wave >> 1;   // wave row (0..1) -> 64-row slab
    const int wc = wave & 1;    // wave col (0..1) -> 64-col slab

    const float alpha = *a_ptr;
    const float beta  = *b_ptr;

    int4v acc[4][4] = {};  // 64 AGPRs

    const int fr  = lane & 15;
    const int gw  = lane >> 4;
    const int fko = (gw ^ ((fr >> 1) & 3)) * 16;

    int s = 0;
    for (int t = 0; t < 64; ++t) {
        while (*(volatile int*)&ready[s] < t + 1)
            __builtin_amdgcn_s_sleep(1);
        __threadfence_block();  // no data read hoisted above the flag

        int4v af[4], bf[4];
#pragma unroll
        for (int i = 0; i < 4; ++i)
            af[i] = *(const int4v*)&As[s][(wr * 64 + i * 16 + fr) * 64 + fko];
#pragma unroll
        for (int j = 0; j < 4; ++j)
            bf[j] = *(const int4v*)&Bs[s][(wc * 64 + j * 16 + fr) * 64 + fko];

        __threadfence_block();  // reads retired before releasing the slot
        if (lane == 0) atomicAdd(&done[s], 1);

#pragma unroll
        for (int i = 0; i < 4; ++i)
#pragma unroll
            for (int j = 0; j < 4; ++j)
                acc[i][j] = __builtin_amdgcn_mfma_i32_16x16x64_i8(
                    af[i], bf[j], acc[i][j], 0, 0, 0);

        s = (s == 2) ? 0 : s + 1;
    }

    // Epilogue: C/D layout col = lane&15, row = (lane>>4)*4 + reg.
    const int orow = (lane >> 4) * 4;
    const int ocol = lane & 15;
#pragma unroll
    for (int j = 0; j < 4; ++j) {
        const int gn = n0 + wc * 64 + j * 16 + ocol;
        const float bb = beta * (float)bias[gn];
#pragma unroll
        for (int i = 0; i < 4; ++i) {
            const int gm = m0 + wr * 64 + i * 16 + orow;
#pragma unroll
            for (int r = 0; r < 4; ++r) {
                float v = alpha * (float)acc[i][j][r] + bb;
                v = rintf(v);                       // round half-to-even (numpy)
                v = fminf(fmaxf(v, -128.0f), 127.0f);
                out[(size_t)(gm + r) * N_DIM + gn] = (int32_t)v;
            }
        }
    }
}

// ---------------------------------------------------------------------------
extern "C" void kernel_launch(void* const* d_in, const int* in_sizes, int n_in,
                              void* d_out, int out_size, void* d_ws, size_t ws_size,
                              hipStream_t stream) {
    const int*   x    = (const int*)d_in[0];    // [M, K] widened int8
    const int*   w    = (const int*)d_in[1];    // [N, K] widened int8
    const int*   bias = (const int*)d_in[2];    // [N]
    const float* a    = (const float*)d_in[3];  // alpha scalar
    const float* b    = (const float*)d_in[4];  // beta scalar
    int32_t*     out  = (int32_t*)d_out;        // [M, N]

    char* xq = (char*)d_ws;                     // 32 MiB packed x
    const int nx   = (M_DIM * K_DIM) / 4;       // int4-groups in x
    const int nw   = (N_DIM * K_DIM) / 4;
    const int ntot = nx + nw;
    pack_kernel<<<(ntot + 255) / 256, 256, 0, stream>>>(
        (const int4*)x, (const int4*)w, (unsigned int*)xq, nx, ntot);

    char* wq = xq + (size_t)M_DIM * K_DIM;      // 16 MiB packed weight

    dim3 grid(N_DIM / 128, M_DIM / 128);        // 32 x 64 = 2048 blocks
    gemm_i8_kernel<<<grid, 512, 0, stream>>>(xq, wq, bias, a, b, out);
}